// Round 9
// baseline (229.900 us; speedup 1.0000x reference)
//
#include <hip/hip_runtime.h>
#include <math.h>

#define BB 8
#define CC 256
#define HH 64
#define WW 64
#define H2 32
#define W2 32
#define NPIX (BB*HH*WW)
#define EPSV 1e-5f

typedef unsigned short ushortT;
using short8  = __attribute__((ext_vector_type(8))) short;
using floatx4 = __attribute__((ext_vector_type(4))) float;

__device__ inline float b2f(ushortT u) {
    unsigned int x = ((unsigned int)u) << 16;
    float f; __builtin_memcpy(&f, &x, 4); return f;
}
__device__ inline ushortT f2b(float f) {
    unsigned int x; __builtin_memcpy(&x, &f, 4);
    unsigned int r = x + 0x7fffu + ((x >> 16) & 1u);   // RNE
    return (ushortT)(r >> 16);
}

// ---------------- K0: weights -> fragment-ordered bf16 B ----------------
// Bfrag[slot*8+j], slot = (ntile*8 + ktile)*64 + lane,
// element = W[k][n] with n = ntile*16 + (lane&15), k = ktile*32 + (lane>>4)*8 + j.
__global__ __launch_bounds__(256) void k0_prep(const float* __restrict__ in_w,
        const float* __restrict__ out_w, ushortT* __restrict__ BfIn,
        ushortT* __restrict__ BfOut) {
    int g = blockIdx.x * 256 + threadIdx.x;          // 0..16383
    const float* W = (g < 8192) ? in_w : out_w;
    ushortT* D = (g < 8192) ? BfIn : BfOut;
    int s = g & 8191;
    int lane  = s & 63;
    int ktile = (s >> 6) & 7;
    int ntile = s >> 9;
    int n = ntile * 16 + (lane & 15);
    int k = ktile * 32 + (lane >> 4) * 8;
    short8 o;
    #pragma unroll
    for (int j = 0; j < 8; ++j)
        o[j] = (short)f2b(W[(size_t)(k + j) * CC + n]);
    *(short8*)(D + (size_t)s * 8) = o;
}

// ---------------- K1: bilinear 2x upsample of x2, |x21-x22| -> guide NHWC bf16 ----------------
__global__ __launch_bounds__(256) void k1_guide(const float* __restrict__ x2,
                                                ushortT* __restrict__ guide) {
    int blk = blockIdx.x;
    int c0 = (blk & 3) * 64;
    int y  = (blk >> 2) & 63;
    int b  = blk >> 8;
    int bb = b & 3;
    __shared__ float tile[64][65];
    int t = threadIdx.x;
    int x = t & 63;

    float sx = 0.5f * x - 0.25f;
    float sy = 0.5f * y - 0.25f;
    float fx0 = floorf(sx), fy0 = floorf(sy);
    float wx = sx - fx0, wy = sy - fy0;
    int jx0 = (int)fx0, jy0 = (int)fy0;
    int ix0 = max(0, min(W2 - 1, jx0));
    int ix1 = max(0, min(W2 - 1, jx0 + 1));
    int iy0 = max(0, min(H2 - 1, jy0));
    int iy1 = max(0, min(H2 - 1, jy0 + 1));
    float w00 = (1.f - wy) * (1.f - wx), w01 = (1.f - wy) * wx;
    float w10 = wy * (1.f - wx), w11 = wy * wx;
    int o00 = iy0 * W2 + ix0, o01 = iy0 * W2 + ix1;
    int o10 = iy1 * W2 + ix0, o11 = iy1 * W2 + ix1;

    int cl = t >> 6;
    #pragma unroll
    for (int it = 0; it < 16; ++it) {
        int c = cl + it * 4;
        const float* p1 = x2 + (size_t)((bb * CC + c0 + c) * H2) * W2;
        const float* p2 = x2 + (size_t)(((bb + 4) * CC + c0 + c) * H2) * W2;
        float v1 = w00 * p1[o00] + w01 * p1[o01] + w10 * p1[o10] + w11 * p1[o11];
        float v2 = w00 * p2[o00] + w01 * p2[o01] + w10 * p2[o10] + w11 * p2[o11];
        tile[c][x] = fabsf(v1 - v2);
    }
    __syncthreads();
    #pragma unroll
    for (int it = 0; it < 16; ++it) {
        int idx = t + it * 256;
        int cw = idx & 63;
        int xw = idx >> 6;
        guide[(size_t)((b * HH + y) * WW + xw) * CC + c0 + cw] = f2b(tile[cw][xw]);
    }
}

// ---------------- K2a: dwconv3x3 + LN + GELU -> feat NHWC bf16 ----------------
__global__ __launch_bounds__(256) void k2a_feat(const ushortT* __restrict__ guide,
        const float* __restrict__ dw_w, const float* __restrict__ dw_b,
        const float* __restrict__ ln_g, const float* __restrict__ ln_b,
        ushortT* __restrict__ feat) {
    int blk = ((blockIdx.x & 7) << 9) | (blockIdx.x >> 3);   // XCD-chunked bijection (4096)
    int p0 = blk * 8;
    int t = threadIdx.x;
    int px = t >> 5, cg = t & 31, c0 = cg * 8;
    int p = p0 + px;
    int x = p & 63, y = (p >> 6) & 63, b = p >> 12;

    __shared__ float Wl[3072];
    #pragma unroll
    for (int i = 0; i < 12; ++i) {
        int idx = t + i * 256;
        float w;
        if (idx < 2304)      w = dw_w[idx];
        else if (idx < 2560) w = dw_b[idx - 2304];
        else if (idx < 2816) w = ln_g[idx - 2560];
        else                 w = ln_b[idx - 2816];
        Wl[idx] = w;
    }
    __syncthreads();

    float f[8];
    #pragma unroll
    for (int j = 0; j < 8; ++j) f[j] = Wl[2304 + c0 + j];
    #pragma unroll
    for (int tap = 0; tap < 9; ++tap) {
        int dy = tap / 3 - 1, dx = tap % 3 - 1;
        int yy = y + dy, xx = x + dx;
        if (yy >= 0 && yy < HH && xx >= 0 && xx < WW) {
            short8 v = *(const short8*)(guide + (size_t)((b * HH + yy) * WW + xx) * CC + c0);
            #pragma unroll
            for (int j = 0; j < 8; ++j)
                f[j] = fmaf(b2f((ushortT)v[j]), Wl[tap * CC + c0 + j], f[j]);
        }
    }
    float s1 = 0.f, s2 = 0.f;
    #pragma unroll
    for (int j = 0; j < 8; ++j) { s1 += f[j]; s2 += f[j] * f[j]; }
    #pragma unroll
    for (int off = 16; off; off >>= 1) {
        s1 += __shfl_xor(s1, off);
        s2 += __shfl_xor(s2, off);
    }
    float mean = s1 * (1.0f / CC);
    float var  = s2 * (1.0f / CC) - mean * mean;
    float rs = rsqrtf(var + EPSV);
    short8 sv;
    #pragma unroll
    for (int j = 0; j < 8; ++j) {
        float v = (f[j] - mean) * rs * Wl[2560 + c0 + j] + Wl[2816 + c0 + j];
        float u2 = 1.5957691216057308f * (v + 0.044715f * v * v * v);
        v = v * __frcp_rn(1.0f + __expf(-u2));
        sv[j] = (short)f2b(v);
    }
    *(short8*)(feat + (size_t)p * CC + c0) = sv;
}

// ---------------- K2b: offmask = feat @ [off_w|mask_w] + bias, softmax(mask) ----------------
__global__ __launch_bounds__(256) void k2b_heads(const ushortT* __restrict__ feat,
        const float* __restrict__ off_w, const float* __restrict__ off_b,
        const float* __restrict__ mask_w, const float* __restrict__ mask_b,
        float* __restrict__ offmask) {
    int p0 = blockIdx.x * 64;
    int t = threadIdx.x;
    __shared__ float Wc[CC * 32];
    __shared__ float As[64 * 36];

    for (int idx = t; idx < CC * 32; idx += 256) {
        int k = idx >> 5, j = idx & 31;
        float w = 0.f;
        if (j < 18)      w = off_w[k * 18 + j];
        else if (j < 27) w = mask_w[k * 9 + (j - 18)];
        Wc[idx] = w;
    }

    int tx = t & 7, ty = t >> 3;
    int n0 = tx * 4, m0 = ty * 2;
    float acc[2][4] = {};

    for (int k0 = 0; k0 < CC; k0 += 32) {
        {
            int m = t >> 2, kq = (t & 3) * 8;
            short8 v = *(const short8*)(feat + (size_t)(p0 + m) * CC + k0 + kq);
            #pragma unroll
            for (int j = 0; j < 8; ++j)
                As[m * 36 + kq + j] = b2f((ushortT)v[j]);
        }
        __syncthreads();
        #pragma unroll
        for (int kk = 0; kk < 32; ++kk) {
            float a0 = As[m0 * 36 + kk];
            float a1 = As[(m0 + 1) * 36 + kk];
            const float* bp = Wc + (k0 + kk) * 32 + n0;
            #pragma unroll
            for (int ni = 0; ni < 4; ++ni) {
                float bw = bp[ni];
                acc[0][ni] = fmaf(a0, bw, acc[0][ni]);
                acc[1][ni] = fmaf(a1, bw, acc[1][ni]);
            }
        }
        __syncthreads();
    }

    float* O = As;
    #pragma unroll
    for (int ni = 0; ni < 4; ++ni) {
        int j = n0 + ni;
        float bias = (j < 18) ? off_b[j] : ((j < 27) ? mask_b[j - 18] : 0.f);
        O[m0 * 36 + j] = acc[0][ni] + bias;
        O[(m0 + 1) * 36 + j] = acc[1][ni] + bias;
    }
    __syncthreads();
    if (t < 64) {
        float* row = O + t * 36 + 18;
        float mx = row[0];
        #pragma unroll
        for (int k = 1; k < 9; ++k) mx = fmaxf(mx, row[k]);
        float e9[9], ssum = 0.f;
        #pragma unroll
        for (int k = 0; k < 9; ++k) { e9[k] = __expf(row[k] - mx); ssum += e9[k]; }
        float inv = __frcp_rn(ssum);
        #pragma unroll
        for (int k = 0; k < 9; ++k) row[k] = e9[k] * inv;
    }
    __syncthreads();
    #pragma unroll
    for (int i = 0; i < 8; ++i) {
        int idx = t + i * 256;
        int pp = idx >> 5, j = idx & 31;
        offmask[(size_t)(p0 + pp) * 32 + j] = O[pp * 36 + j];
    }
}

// ---------------- K3: xproj = NHWC(x1) @ BfIn + in_b  [MFMA, BM=32, BN=256, no K barriers] ------
__global__ __launch_bounds__(256, 4) void k3_mfma(const float* __restrict__ x1,
        const ushortT* __restrict__ Bf, const float* __restrict__ bias,
        ushortT* __restrict__ C) {
    __shared__ __align__(16) short Asb[32 * 264];   // 16896 B
    int t = threadIdx.x;
    int bm = ((blockIdx.x & 7) << 7) | (blockIdx.x >> 3);   // XCD-chunked bijection (1024)
    int m0 = bm * 32;
    int b = m0 >> 12, y = (m0 >> 6) & 63, xb = m0 & 63;
    int lane = t & 63, w = t >> 6;
    int cl = lane & 15, rg = lane >> 4;

    #pragma unroll
    for (int i = 0; i < 8; ++i) {
        int e = t + i * 256;            // 0..2047
        int ch = e >> 3, xq = (e & 7) * 4;
        float4 v = *(const float4*)(x1 + (size_t)((b * CC + ch) * HH + y) * WW + xb + xq);
        Asb[(xq + 0) * 264 + ch] = (short)f2b(v.x);
        Asb[(xq + 1) * 264 + ch] = (short)f2b(v.y);
        Asb[(xq + 2) * 264 + ch] = (short)f2b(v.z);
        Asb[(xq + 3) * 264 + ch] = (short)f2b(v.w);
    }
    __syncthreads();

    floatx4 acc[2][4];
    floatx4 zero = {0.f, 0.f, 0.f, 0.f};
    #pragma unroll
    for (int i = 0; i < 2; ++i)
        #pragma unroll
        for (int j = 0; j < 4; ++j) acc[i][j] = zero;

    #pragma unroll
    for (int kt = 0; kt < 8; ++kt) {
        short8 af[2], bfr[4];
        #pragma unroll
        for (int f = 0; f < 2; ++f)
            af[f] = *(const short8*)(&Asb[(f * 16 + cl) * 264 + kt * 32 + rg * 8]);
        #pragma unroll
        for (int fc = 0; fc < 4; ++fc)
            bfr[fc] = *(const short8*)(Bf + ((size_t)((w * 4 + fc) * 8 + kt) * 64 + lane) * 8);
        #pragma unroll
        for (int fr = 0; fr < 2; ++fr)
            #pragma unroll
            for (int fc = 0; fc < 4; ++fc)
                acc[fr][fc] = __builtin_amdgcn_mfma_f32_16x16x32_bf16(
                    af[fr], bfr[fc], acc[fr][fc], 0, 0, 0);
    }
    __syncthreads();

    short* Co = Asb;
    #pragma unroll
    for (int fc = 0; fc < 4; ++fc) {
        int n = w * 64 + fc * 16 + cl;
        float bv = bias[n];
        #pragma unroll
        for (int fr = 0; fr < 2; ++fr) {
            int mr = fr * 16 + rg * 4;
            #pragma unroll
            for (int j = 0; j < 4; ++j)
                Co[(mr + j) * 264 + n] = (short)f2b(acc[fr][fc][j] + bv);
        }
    }
    __syncthreads();
    #pragma unroll
    for (int i = 0; i < 4; ++i) {
        int e = t + i * 256;
        int px = e >> 5, oct = e & 31;
        *(short8*)(C + (size_t)(m0 + px) * CC + oct * 8) = *(const short8*)(&Co[px * 264 + oct * 8]);
    }
}

// ---------------- K45: fused deformable gather + out-proj GEMM + BN + ReLU + residual ----------
// grid: 1024 M-tiles (XCD-chunked), 256 threads = 4 waves, BM=32 px, BN=256, BK=64.
// K-loop gather (round-8 structure, 50us) with 4 blocks/CU (grid was the occupancy cap).
__global__ __launch_bounds__(256, 4) void k45_fused(const ushortT* __restrict__ xproj,
        const float* __restrict__ offmask, const ushortT* __restrict__ Bf,
        const float* __restrict__ out_b,
        const float* __restrict__ bn_g, const float* __restrict__ bn_b,
        const float* __restrict__ bn_mean, const float* __restrict__ bn_var,
        const float* __restrict__ x1, float* __restrict__ out) {
    __shared__ __align__(16) char smem[18560];
    short* Asb     = (short*)smem;                   // [32][72]   4608 B
    float* s_w     = (float*)(smem + 4608);          // [32][9][4] 4608 B
    int*   s_idx   = (int*)(smem + 9216);            // [32][9][4] 4608 B
    float* s_scale = (float*)(smem + 16512);         // [256] 1024 B (after Lo region)
    float* s_shift = (float*)(smem + 17536);         // [256] 1024 B
    float* Lo      = (float*)smem;                   // epi reuse: [32][129] f32 = 16512 B

    int t = threadIdx.x;
    int bm = ((blockIdx.x & 7) << 7) | (blockIdx.x >> 3);   // XCD-chunked bijection (1024)
    int m0 = bm * 32;
    int b = m0 >> 12, y = (m0 >> 6) & 63, xb = m0 & 63;
    int lane = t & 63, w = t >> 6;
    int cl = lane & 15, rg = lane >> 4;

    {   // fold bias+BN into scale/shift (256 threads -> 1 each)
        float scale = bn_g[t] * rsqrtf(bn_var[t] + EPSV);
        s_scale[t] = scale;
        s_shift[t] = out_b[t] * scale + bn_b[t] - bn_mean[t] * scale;
    }
    // stage sampling weights/indices for the 32 pixels (288 items)
    for (int e = t; e < 288; e += 256) {
        int px = e / 9, k = e - px * 9;
        int p = m0 + px;
        float dx = offmask[(size_t)p * 32 + 2 * k];
        float dy = offmask[(size_t)p * 32 + 2 * k + 1];
        float m  = offmask[(size_t)p * 32 + 18 + k];
        float py  = (float)y + (float)(k / 3 - 1) + dy;
        float pxf = (float)(xb + px) + (float)(k % 3 - 1) + dx;
        float y0f = floorf(py), x0f = floorf(pxf);
        float wy = py - y0f, wx = pxf - x0f;
        int y0 = (int)y0f, x0 = (int)x0f;
        int y1 = y0 + 1, x1i = x0 + 1;
        float vy0 = (y0 >= 0 && y0 < HH) ? 1.f : 0.f;
        float vy1 = (y1 >= 0 && y1 < HH) ? 1.f : 0.f;
        float vx0 = (x0 >= 0 && x0 < WW) ? 1.f : 0.f;
        float vx1 = (x1i >= 0 && x1i < WW) ? 1.f : 0.f;
        int yc0 = max(0, min(HH - 1, y0)), yc1 = max(0, min(HH - 1, y1));
        int xc0 = max(0, min(WW - 1, x0)), xc1 = max(0, min(WW - 1, x1i));
        int base = b * HH * WW;
        int o = (px * 9 + k) * 4;
        s_idx[o + 0] = (base + yc0 * WW + xc0) * CC;
        s_idx[o + 1] = (base + yc0 * WW + xc1) * CC;
        s_idx[o + 2] = (base + yc1 * WW + xc0) * CC;
        s_idx[o + 3] = (base + yc1 * WW + xc1) * CC;
        s_w[o + 0] = m * (1.f - wy) * (1.f - wx) * vy0 * vx0;
        s_w[o + 1] = m * (1.f - wy) * wx * vy0 * vx1;
        s_w[o + 2] = m * wy * (1.f - wx) * vy1 * vx0;
        s_w[o + 3] = m * wy * wx * vy1 * vx1;
    }
    __syncthreads();

    floatx4 acc[2][4];
    floatx4 zero = {0.f, 0.f, 0.f, 0.f};
    #pragma unroll
    for (int i = 0; i < 2; ++i)
        #pragma unroll
        for (int j = 0; j < 4; ++j) acc[i][j] = zero;

    for (int k0 = 0; k0 < CC; k0 += 64) {
        // gather-stage A: 32 px x 64 ch, one octet-item per thread, split accumulator chains
        {
            int px = t >> 3, o8 = t & 7;
            int c = k0 + o8 * 8;
            const float* wp = s_w  + px * 36;
            const int*   ip = s_idx + px * 36;
            float f0[8] = {}, f1[8] = {};
            #pragma unroll
            for (int q = 0; q < 36; q += 2) {
                float w0 = wp[q], w1 = wp[q + 1];
                short8 v0 = *(const short8*)(xproj + ip[q] + c);
                short8 v1 = *(const short8*)(xproj + ip[q + 1] + c);
                #pragma unroll
                for (int j = 0; j < 8; ++j) {
                    f0[j] = fmaf(w0, b2f((ushortT)v0[j]), f0[j]);
                    f1[j] = fmaf(w1, b2f((ushortT)v1[j]), f1[j]);
                }
            }
            short8 sv;
            #pragma unroll
            for (int j = 0; j < 8; ++j) sv[j] = (short)f2b(f0[j] + f1[j]);
            *(short8*)(&Asb[px * 72 + o8 * 8]) = sv;
        }
        __syncthreads();
        int kt0 = k0 >> 5;
        #pragma unroll
        for (int kk = 0; kk < 2; ++kk) {
            short8 af[2], bfr[4];
            #pragma unroll
            for (int f = 0; f < 2; ++f)
                af[f] = *(const short8*)(&Asb[(f * 16 + cl) * 72 + kk * 32 + rg * 8]);
            #pragma unroll
            for (int fc = 0; fc < 4; ++fc)
                bfr[fc] = *(const short8*)(Bf + ((size_t)((w * 4 + fc) * 8 + kt0 + kk) * 64 + lane) * 8);
            #pragma unroll
            for (int fr = 0; fr < 2; ++fr)
                #pragma unroll
                for (int fc = 0; fc < 4; ++fc)
                    acc[fr][fc] = __builtin_amdgcn_mfma_f32_16x16x32_bf16(
                        af[fr], bfr[fc], acc[fr][fc], 0, 0, 0);
        }
        __syncthreads();
    }

    // epilogue: 2 phases of 128 channels; Lo bounce -> fused BN+ReLU+residual NCHW stores
    #pragma unroll
    for (int ph = 0; ph < 2; ++ph) {
        if ((w >> 1) == ph) {
            #pragma unroll
            for (int fc = 0; fc < 4; ++fc) {
                int cloc = (w & 1) * 64 + fc * 16 + cl;
                #pragma unroll
                for (int fr = 0; fr < 2; ++fr) {
                    int mr = fr * 16 + rg * 4;
                    #pragma unroll
                    for (int j = 0; j < 4; ++j)
                        Lo[(mr + j) * 129 + cloc] = acc[fr][fc][j];
                }
            }
        }
        __syncthreads();
        #pragma unroll
        for (int i = 0; i < 16; ++i) {
            int e = t + i * 256;              // 0..4095 = 32 px x 128 ch
            int xl = e & 31, cw = e >> 5;
            int co = ph * 128 + cw;
            float val = Lo[xl * 129 + cw] * s_scale[co] + s_shift[co];
            val = fmaxf(val, 0.f);
            size_t g = (size_t)((b * CC + co) * HH + y) * WW + xb + xl;
            out[g] = val + x1[g];
        }
        __syncthreads();
    }
}

extern "C" void kernel_launch(void* const* d_in, const int* in_sizes, int n_in,
                              void* d_out, int out_size, void* d_ws, size_t ws_size,
                              hipStream_t stream) {
    const float* x1     = (const float*)d_in[0];
    const float* x2     = (const float*)d_in[1];
    const float* dw_w   = (const float*)d_in[2];
    const float* dw_b   = (const float*)d_in[3];
    const float* ln_g   = (const float*)d_in[4];
    const float* ln_b   = (const float*)d_in[5];
    const float* off_w  = (const float*)d_in[6];
    const float* off_b  = (const float*)d_in[7];
    const float* mask_w = (const float*)d_in[8];
    const float* mask_b = (const float*)d_in[9];
    const float* in_w   = (const float*)d_in[10];
    const float* in_b   = (const float*)d_in[11];
    const float* out_w  = (const float*)d_in[12];
    const float* out_b  = (const float*)d_in[13];
    const float* bn_g   = (const float*)d_in[14];
    const float* bn_b   = (const float*)d_in[15];
    const float* bn_mean= (const float*)d_in[16];
    const float* bn_var = (const float*)d_in[17];
    float* out = (float*)d_out;

    char* wsb = (char*)d_ws;
    const size_t SZ = (size_t)NPIX * CC * 2;        // 16.78 MB per bf16 tensor
    ushortT* guide   = (ushortT*)wsb;               // slot0 (k1 out, k2a in)
    ushortT* feat    = (ushortT*)(wsb + SZ);        // slot1 (k2a out, k2b in)
    float*   offmask = (float*)(wsb + 2 * SZ);      // 4.19 MB
    ushortT* BfIn    = (ushortT*)(wsb + 2 * SZ + (size_t)NPIX * 32 * 4);
    ushortT* BfOut   = BfIn + CC * CC;
    ushortT* xproj   = guide;                       // guide dead after k2a -> alias

    hipLaunchKernelGGL(k0_prep,   dim3(64),   dim3(256), 0, stream, in_w, out_w, BfIn, BfOut);
    hipLaunchKernelGGL(k1_guide,  dim3(2048), dim3(256), 0, stream, x2, guide);
    hipLaunchKernelGGL(k2a_feat,  dim3(4096), dim3(256), 0, stream, guide, dw_w, dw_b,
                       ln_g, ln_b, feat);
    hipLaunchKernelGGL(k2b_heads, dim3(512),  dim3(256), 0, stream, feat, off_w, off_b,
                       mask_w, mask_b, offmask);
    hipLaunchKernelGGL(k3_mfma,   dim3(1024), dim3(256), 0, stream, x1, BfIn, in_b, xproj);
    hipLaunchKernelGGL(k45_fused, dim3(1024), dim3(256), 0, stream, xproj, offmask, BfOut,
                       out_b, bn_g, bn_b, bn_mean, bn_var, x1, out);
}

// Round 10
// 131.301 us; speedup vs baseline: 1.7509x; 1.7509x over previous
//
#include <hip/hip_runtime.h>
#include <math.h>

#define BB 8
#define CC 256
#define HH 64
#define WW 64
#define H2 32
#define W2 32
#define NPIX (BB*HH*WW)
#define EPSV 1e-5f

typedef unsigned short ushortT;
using short8  = __attribute__((ext_vector_type(8))) short;
using floatx4 = __attribute__((ext_vector_type(4))) float;

__device__ inline float b2f(ushortT u) {
    unsigned int x = ((unsigned int)u) << 16;
    float f; __builtin_memcpy(&f, &x, 4); return f;
}
__device__ inline ushortT f2b(float f) {
    unsigned int x; __builtin_memcpy(&x, &f, 4);
    unsigned int r = x + 0x7fffu + ((x >> 16) & 1u);   // RNE
    return (ushortT)(r >> 16);
}

// ---------------- K0: weights -> fragment-ordered bf16 B ----------------
// Bfrag[slot*8+j], slot = (ntile*8 + ktile)*64 + lane,
// element = W[k][n] with n = ntile*16 + (lane&15), k = ktile*32 + (lane>>4)*8 + j.
__global__ __launch_bounds__(256) void k0_prep(const float* __restrict__ in_w,
        const float* __restrict__ out_w, ushortT* __restrict__ BfIn,
        ushortT* __restrict__ BfOut) {
    int g = blockIdx.x * 256 + threadIdx.x;          // 0..16383
    const float* W = (g < 8192) ? in_w : out_w;
    ushortT* D = (g < 8192) ? BfIn : BfOut;
    int s = g & 8191;
    int lane  = s & 63;
    int ktile = (s >> 6) & 7;
    int ntile = s >> 9;
    int n = ntile * 16 + (lane & 15);
    int k = ktile * 32 + (lane >> 4) * 8;
    short8 o;
    #pragma unroll
    for (int j = 0; j < 8; ++j)
        o[j] = (short)f2b(W[(size_t)(k + j) * CC + n]);
    *(short8*)(D + (size_t)s * 8) = o;
}

// ---------------- K1: bilinear 2x upsample of x2, |x21-x22| -> guide NHWC bf16 ----------------
__global__ __launch_bounds__(256) void k1_guide(const float* __restrict__ x2,
                                                ushortT* __restrict__ guide) {
    int blk = blockIdx.x;
    int c0 = (blk & 3) * 64;
    int y  = (blk >> 2) & 63;
    int b  = blk >> 8;
    int bb = b & 3;
    __shared__ float tile[64][65];
    int t = threadIdx.x;
    int x = t & 63;

    float sx = 0.5f * x - 0.25f;
    float sy = 0.5f * y - 0.25f;
    float fx0 = floorf(sx), fy0 = floorf(sy);
    float wx = sx - fx0, wy = sy - fy0;
    int jx0 = (int)fx0, jy0 = (int)fy0;
    int ix0 = max(0, min(W2 - 1, jx0));
    int ix1 = max(0, min(W2 - 1, jx0 + 1));
    int iy0 = max(0, min(H2 - 1, jy0));
    int iy1 = max(0, min(H2 - 1, jy0 + 1));
    float w00 = (1.f - wy) * (1.f - wx), w01 = (1.f - wy) * wx;
    float w10 = wy * (1.f - wx), w11 = wy * wx;
    int o00 = iy0 * W2 + ix0, o01 = iy0 * W2 + ix1;
    int o10 = iy1 * W2 + ix0, o11 = iy1 * W2 + ix1;

    int cl = t >> 6;
    #pragma unroll
    for (int it = 0; it < 16; ++it) {
        int c = cl + it * 4;
        const float* p1 = x2 + (size_t)((bb * CC + c0 + c) * H2) * W2;
        const float* p2 = x2 + (size_t)(((bb + 4) * CC + c0 + c) * H2) * W2;
        float v1 = w00 * p1[o00] + w01 * p1[o01] + w10 * p1[o10] + w11 * p1[o11];
        float v2 = w00 * p2[o00] + w01 * p2[o01] + w10 * p2[o10] + w11 * p2[o11];
        tile[c][x] = fabsf(v1 - v2);
    }
    __syncthreads();
    #pragma unroll
    for (int it = 0; it < 16; ++it) {
        int idx = t + it * 256;
        int cw = idx & 63;
        int xw = idx >> 6;
        guide[(size_t)((b * HH + y) * WW + xw) * CC + c0 + cw] = f2b(tile[cw][xw]);
    }
}

// ---------------- K2a: dwconv3x3 + LN + GELU -> feat NHWC bf16 ----------------
__global__ __launch_bounds__(256) void k2a_feat(const ushortT* __restrict__ guide,
        const float* __restrict__ dw_w, const float* __restrict__ dw_b,
        const float* __restrict__ ln_g, const float* __restrict__ ln_b,
        ushortT* __restrict__ feat) {
    int blk = ((blockIdx.x & 7) << 9) | (blockIdx.x >> 3);   // XCD-chunked bijection (4096)
    int p0 = blk * 8;
    int t = threadIdx.x;
    int px = t >> 5, cg = t & 31, c0 = cg * 8;
    int p = p0 + px;
    int x = p & 63, y = (p >> 6) & 63, b = p >> 12;

    __shared__ float Wl[3072];
    #pragma unroll
    for (int i = 0; i < 12; ++i) {
        int idx = t + i * 256;
        float w;
        if (idx < 2304)      w = dw_w[idx];
        else if (idx < 2560) w = dw_b[idx - 2304];
        else if (idx < 2816) w = ln_g[idx - 2560];
        else                 w = ln_b[idx - 2816];
        Wl[idx] = w;
    }
    __syncthreads();

    float f[8];
    #pragma unroll
    for (int j = 0; j < 8; ++j) f[j] = Wl[2304 + c0 + j];
    #pragma unroll
    for (int tap = 0; tap < 9; ++tap) {
        int dy = tap / 3 - 1, dx = tap % 3 - 1;
        int yy = y + dy, xx = x + dx;
        if (yy >= 0 && yy < HH && xx >= 0 && xx < WW) {
            short8 v = *(const short8*)(guide + (size_t)((b * HH + yy) * WW + xx) * CC + c0);
            #pragma unroll
            for (int j = 0; j < 8; ++j)
                f[j] = fmaf(b2f((ushortT)v[j]), Wl[tap * CC + c0 + j], f[j]);
        }
    }
    float s1 = 0.f, s2 = 0.f;
    #pragma unroll
    for (int j = 0; j < 8; ++j) { s1 += f[j]; s2 += f[j] * f[j]; }
    #pragma unroll
    for (int off = 16; off; off >>= 1) {
        s1 += __shfl_xor(s1, off);
        s2 += __shfl_xor(s2, off);
    }
    float mean = s1 * (1.0f / CC);
    float var  = s2 * (1.0f / CC) - mean * mean;
    float rs = rsqrtf(var + EPSV);
    short8 sv;
    #pragma unroll
    for (int j = 0; j < 8; ++j) {
        float v = (f[j] - mean) * rs * Wl[2560 + c0 + j] + Wl[2816 + c0 + j];
        float u2 = 1.5957691216057308f * (v + 0.044715f * v * v * v);
        v = v * __frcp_rn(1.0f + __expf(-u2));
        sv[j] = (short)f2b(v);
    }
    *(short8*)(feat + (size_t)p * CC + c0) = sv;
}

// ---------------- K2b: offmask = feat @ [off_w|mask_w] + bias, softmax(mask) ----------------
__global__ __launch_bounds__(256) void k2b_heads(const ushortT* __restrict__ feat,
        const float* __restrict__ off_w, const float* __restrict__ off_b,
        const float* __restrict__ mask_w, const float* __restrict__ mask_b,
        float* __restrict__ offmask) {
    int p0 = blockIdx.x * 64;
    int t = threadIdx.x;
    __shared__ float Wc[CC * 32];
    __shared__ float As[64 * 36];

    for (int idx = t; idx < CC * 32; idx += 256) {
        int k = idx >> 5, j = idx & 31;
        float w = 0.f;
        if (j < 18)      w = off_w[k * 18 + j];
        else if (j < 27) w = mask_w[k * 9 + (j - 18)];
        Wc[idx] = w;
    }

    int tx = t & 7, ty = t >> 3;
    int n0 = tx * 4, m0 = ty * 2;
    float acc[2][4] = {};

    for (int k0 = 0; k0 < CC; k0 += 32) {
        {
            int m = t >> 2, kq = (t & 3) * 8;
            short8 v = *(const short8*)(feat + (size_t)(p0 + m) * CC + k0 + kq);
            #pragma unroll
            for (int j = 0; j < 8; ++j)
                As[m * 36 + kq + j] = b2f((ushortT)v[j]);
        }
        __syncthreads();
        #pragma unroll
        for (int kk = 0; kk < 32; ++kk) {
            float a0 = As[m0 * 36 + kk];
            float a1 = As[(m0 + 1) * 36 + kk];
            const float* bp = Wc + (k0 + kk) * 32 + n0;
            #pragma unroll
            for (int ni = 0; ni < 4; ++ni) {
                float bw = bp[ni];
                acc[0][ni] = fmaf(a0, bw, acc[0][ni]);
                acc[1][ni] = fmaf(a1, bw, acc[1][ni]);
            }
        }
        __syncthreads();
    }

    float* O = As;
    #pragma unroll
    for (int ni = 0; ni < 4; ++ni) {
        int j = n0 + ni;
        float bias = (j < 18) ? off_b[j] : ((j < 27) ? mask_b[j - 18] : 0.f);
        O[m0 * 36 + j] = acc[0][ni] + bias;
        O[(m0 + 1) * 36 + j] = acc[1][ni] + bias;
    }
    __syncthreads();
    if (t < 64) {
        float* row = O + t * 36 + 18;
        float mx = row[0];
        #pragma unroll
        for (int k = 1; k < 9; ++k) mx = fmaxf(mx, row[k]);
        float e9[9], ssum = 0.f;
        #pragma unroll
        for (int k = 0; k < 9; ++k) { e9[k] = __expf(row[k] - mx); ssum += e9[k]; }
        float inv = __frcp_rn(ssum);
        #pragma unroll
        for (int k = 0; k < 9; ++k) row[k] = e9[k] * inv;
    }
    __syncthreads();
    #pragma unroll
    for (int i = 0; i < 8; ++i) {
        int idx = t + i * 256;
        int pp = idx >> 5, j = idx & 31;
        offmask[(size_t)(p0 + pp) * 32 + j] = O[pp * 36 + j];
    }
}

// ---------------- K3: xproj = NHWC(x1) @ BfIn + in_b  [MFMA, BM=32, BN=256, no K barriers] ------
__global__ __launch_bounds__(256, 4) void k3_mfma(const float* __restrict__ x1,
        const ushortT* __restrict__ Bf, const float* __restrict__ bias,
        ushortT* __restrict__ C) {
    __shared__ __align__(16) short Asb[32 * 264];   // 16896 B
    int t = threadIdx.x;
    int bm = ((blockIdx.x & 7) << 7) | (blockIdx.x >> 3);   // XCD-chunked bijection (1024)
    int m0 = bm * 32;
    int b = m0 >> 12, y = (m0 >> 6) & 63, xb = m0 & 63;
    int lane = t & 63, w = t >> 6;
    int cl = lane & 15, rg = lane >> 4;

    #pragma unroll
    for (int i = 0; i < 8; ++i) {
        int e = t + i * 256;            // 0..2047
        int ch = e >> 3, xq = (e & 7) * 4;
        float4 v = *(const float4*)(x1 + (size_t)((b * CC + ch) * HH + y) * WW + xb + xq);
        Asb[(xq + 0) * 264 + ch] = (short)f2b(v.x);
        Asb[(xq + 1) * 264 + ch] = (short)f2b(v.y);
        Asb[(xq + 2) * 264 + ch] = (short)f2b(v.z);
        Asb[(xq + 3) * 264 + ch] = (short)f2b(v.w);
    }
    __syncthreads();

    floatx4 acc[2][4];
    floatx4 zero = {0.f, 0.f, 0.f, 0.f};
    #pragma unroll
    for (int i = 0; i < 2; ++i)
        #pragma unroll
        for (int j = 0; j < 4; ++j) acc[i][j] = zero;

    #pragma unroll
    for (int kt = 0; kt < 8; ++kt) {
        short8 af[2], bfr[4];
        #pragma unroll
        for (int f = 0; f < 2; ++f)
            af[f] = *(const short8*)(&Asb[(f * 16 + cl) * 264 + kt * 32 + rg * 8]);
        #pragma unroll
        for (int fc = 0; fc < 4; ++fc)
            bfr[fc] = *(const short8*)(Bf + ((size_t)((w * 4 + fc) * 8 + kt) * 64 + lane) * 8);
        #pragma unroll
        for (int fr = 0; fr < 2; ++fr)
            #pragma unroll
            for (int fc = 0; fc < 4; ++fc)
                acc[fr][fc] = __builtin_amdgcn_mfma_f32_16x16x32_bf16(
                    af[fr], bfr[fc], acc[fr][fc], 0, 0, 0);
    }
    __syncthreads();

    short* Co = Asb;
    #pragma unroll
    for (int fc = 0; fc < 4; ++fc) {
        int n = w * 64 + fc * 16 + cl;
        float bv = bias[n];
        #pragma unroll
        for (int fr = 0; fr < 2; ++fr) {
            int mr = fr * 16 + rg * 4;
            #pragma unroll
            for (int j = 0; j < 4; ++j)
                Co[(mr + j) * 264 + n] = (short)f2b(acc[fr][fc][j] + bv);
        }
    }
    __syncthreads();
    #pragma unroll
    for (int i = 0; i < 4; ++i) {
        int e = t + i * 256;
        int px = e >> 5, oct = e & 31;
        *(short8*)(C + (size_t)(m0 + px) * CC + oct * 8) = *(const short8*)(&Co[px * 264 + oct * 8]);
    }
}

// ---------------- K45: fused deformable gather + out-proj GEMM + BN + ReLU + residual ----------
// grid: 512 M-tiles (round-8 mapping), 512 threads = 8 waves, BM=64 px, BN=256, BK=64.
// Memory structure identical to round-8 (27MB fetch / 50us measured); only TLP doubled:
// 8 waves/block, wave w owns 32 output cols (acc[4][2]) -> 2 blocks/CU = 16 waves/CU.
__global__ __launch_bounds__(512, 4) void k45_fused(const ushortT* __restrict__ xproj,
        const float* __restrict__ offmask, const ushortT* __restrict__ Bf,
        const float* __restrict__ out_b,
        const float* __restrict__ bn_g, const float* __restrict__ bn_b,
        const float* __restrict__ bn_mean, const float* __restrict__ bn_var,
        const float* __restrict__ x1, float* __restrict__ out) {
    __shared__ __align__(16) char smem[29696];
    short* Asb     = (short*)smem;                   // [64][72]   9216 B
    float* s_w     = (float*)(smem + 9216);          // [64][9][4] 9216 B
    int*   s_idx   = (int*)(smem + 18432);           // [64][9][4] 9216 B
    float* s_scale = (float*)(smem + 27648);         // [256]      1024 B
    float* s_shift = (float*)(smem + 28672);         // [256]      1024 B
    float* Lo      = (float*)smem;                   // epi reuse: [64][65] f32 = 16640 B

    int t = threadIdx.x;
    int bm = ((blockIdx.x & 7) << 6) | (blockIdx.x >> 3);   // XCD-chunked bijection (512)
    int m0 = bm * 64;
    int b = bm >> 6, y = bm & 63;
    int lane = t & 63, w = t >> 6;
    int cl = lane & 15, rg = lane >> 4;

    if (t < 256) {
        float scale = bn_g[t] * rsqrtf(bn_var[t] + EPSV);
        s_scale[t] = scale;
        s_shift[t] = out_b[t] * scale + bn_b[t] - bn_mean[t] * scale;
    }
    for (int e = t; e < 576; e += 512) {
        int px = e / 9, k = e - px * 9;
        int p = m0 + px;
        float dx = offmask[(size_t)p * 32 + 2 * k];
        float dy = offmask[(size_t)p * 32 + 2 * k + 1];
        float m  = offmask[(size_t)p * 32 + 18 + k];
        float py  = (float)y  + (float)(k / 3 - 1) + dy;
        float pxf = (float)px + (float)(k % 3 - 1) + dx;
        float y0f = floorf(py), x0f = floorf(pxf);
        float wy = py - y0f, wx = pxf - x0f;
        int y0 = (int)y0f, x0 = (int)x0f;
        int y1 = y0 + 1, x1i = x0 + 1;
        float vy0 = (y0 >= 0 && y0 < HH) ? 1.f : 0.f;
        float vy1 = (y1 >= 0 && y1 < HH) ? 1.f : 0.f;
        float vx0 = (x0 >= 0 && x0 < WW) ? 1.f : 0.f;
        float vx1 = (x1i >= 0 && x1i < WW) ? 1.f : 0.f;
        int yc0 = max(0, min(HH - 1, y0)), yc1 = max(0, min(HH - 1, y1));
        int xc0 = max(0, min(WW - 1, x0)), xc1 = max(0, min(WW - 1, x1i));
        int base = b * HH * WW;
        int o = (px * 9 + k) * 4;
        s_idx[o + 0] = (base + yc0 * WW + xc0) * CC;
        s_idx[o + 1] = (base + yc0 * WW + xc1) * CC;
        s_idx[o + 2] = (base + yc1 * WW + xc0) * CC;
        s_idx[o + 3] = (base + yc1 * WW + xc1) * CC;
        s_w[o + 0] = m * (1.f - wy) * (1.f - wx) * vy0 * vx0;
        s_w[o + 1] = m * (1.f - wy) * wx * vy0 * vx1;
        s_w[o + 2] = m * wy * (1.f - wx) * vy1 * vx0;
        s_w[o + 3] = m * wy * wx * vy1 * vx1;
    }
    __syncthreads();

    floatx4 acc[4][2];
    floatx4 zero = {0.f, 0.f, 0.f, 0.f};
    #pragma unroll
    for (int i = 0; i < 4; ++i)
        #pragma unroll
        for (int j = 0; j < 2; ++j) acc[i][j] = zero;

    for (int k0 = 0; k0 < CC; k0 += 64) {
        // gather-stage A: 64 px x 64 ch, one octet-item per thread (round-8 body)
        {
            int px = t >> 3, o8 = t & 7;
            int c = k0 + o8 * 8;
            const float* wp = s_w  + px * 36;
            const int*   ip = s_idx + px * 36;
            float f[8] = {};
            #pragma unroll
            for (int q = 0; q < 36; ++q) {
                float wv = wp[q];
                short8 v = *(const short8*)(xproj + ip[q] + c);
                #pragma unroll
                for (int j = 0; j < 8; ++j)
                    f[j] = fmaf(wv, b2f((ushortT)v[j]), f[j]);
            }
            short8 sv;
            #pragma unroll
            for (int j = 0; j < 8; ++j) sv[j] = (short)f2b(f[j]);
            *(short8*)(&Asb[px * 72 + o8 * 8]) = sv;
        }
        __syncthreads();
        int kt0 = k0 >> 5;
        #pragma unroll
        for (int kk = 0; kk < 2; ++kk) {
            short8 af[4], bfr[2];
            #pragma unroll
            for (int f = 0; f < 4; ++f)
                af[f] = *(const short8*)(&Asb[(f * 16 + cl) * 72 + kk * 32 + rg * 8]);
            #pragma unroll
            for (int fc = 0; fc < 2; ++fc)
                bfr[fc] = *(const short8*)(Bf + ((size_t)((w * 2 + fc) * 8 + kt0 + kk) * 64 + lane) * 8);
            #pragma unroll
            for (int fr = 0; fr < 4; ++fr)
                #pragma unroll
                for (int fc = 0; fc < 2; ++fc)
                    acc[fr][fc] = __builtin_amdgcn_mfma_f32_16x16x32_bf16(
                        af[fr], bfr[fc], acc[fr][fc], 0, 0, 0);
        }
        __syncthreads();
    }

    // epilogue: 4 phases of 64 channels; phase ph owned by waves 2ph, 2ph+1
    #pragma unroll
    for (int ph = 0; ph < 4; ++ph) {
        if ((w >> 1) == ph) {
            #pragma unroll
            for (int fc = 0; fc < 2; ++fc) {
                int cloc = (w & 1) * 32 + fc * 16 + cl;
                #pragma unroll
                for (int fr = 0; fr < 4; ++fr) {
                    int mr = fr * 16 + rg * 4;
                    #pragma unroll
                    for (int j = 0; j < 4; ++j)
                        Lo[(mr + j) * 65 + cloc] = acc[fr][fc][j];
                }
            }
        }
        __syncthreads();
        #pragma unroll
        for (int i = 0; i < 8; ++i) {
            int e = t + i * 512;              // 0..4095 = 64 px x 64 ch
            int xl = e & 63, cw = e >> 6;
            int co = ph * 64 + cw;
            float val = Lo[xl * 65 + cw] * s_scale[co] + s_shift[co];
            val = fmaxf(val, 0.f);
            size_t g = (size_t)((b * CC + co) * HH + y) * WW + xl;
            out[g] = val + x1[g];
        }
        __syncthreads();
    }
}

extern "C" void kernel_launch(void* const* d_in, const int* in_sizes, int n_in,
                              void* d_out, int out_size, void* d_ws, size_t ws_size,
                              hipStream_t stream) {
    const float* x1     = (const float*)d_in[0];
    const float* x2     = (const float*)d_in[1];
    const float* dw_w   = (const float*)d_in[2];
    const float* dw_b   = (const float*)d_in[3];
    const float* ln_g   = (const float*)d_in[4];
    const float* ln_b   = (const float*)d_in[5];
    const float* off_w  = (const float*)d_in[6];
    const float* off_b  = (const float*)d_in[7];
    const float* mask_w = (const float*)d_in[8];
    const float* mask_b = (const float*)d_in[9];
    const float* in_w   = (const float*)d_in[10];
    const float* in_b   = (const float*)d_in[11];
    const float* out_w  = (const float*)d_in[12];
    const float* out_b  = (const float*)d_in[13];
    const float* bn_g   = (const float*)d_in[14];
    const float* bn_b   = (const float*)d_in[15];
    const float* bn_mean= (const float*)d_in[16];
    const float* bn_var = (const float*)d_in[17];
    float* out = (float*)d_out;

    char* wsb = (char*)d_ws;
    const size_t SZ = (size_t)NPIX * CC * 2;        // 16.78 MB per bf16 tensor
    ushortT* guide   = (ushortT*)wsb;               // slot0 (k1 out, k2a in)
    ushortT* feat    = (ushortT*)(wsb + SZ);        // slot1 (k2a out, k2b in)
    float*   offmask = (float*)(wsb + 2 * SZ);      // 4.19 MB
    ushortT* BfIn    = (ushortT*)(wsb + 2 * SZ + (size_t)NPIX * 32 * 4);
    ushortT* BfOut   = BfIn + CC * CC;
    ushortT* xproj   = guide;                       // guide dead after k2a -> alias

    hipLaunchKernelGGL(k0_prep,   dim3(64),   dim3(256), 0, stream, in_w, out_w, BfIn, BfOut);
    hipLaunchKernelGGL(k1_guide,  dim3(2048), dim3(256), 0, stream, x2, guide);
    hipLaunchKernelGGL(k2a_feat,  dim3(4096), dim3(256), 0, stream, guide, dw_w, dw_b,
                       ln_g, ln_b, feat);
    hipLaunchKernelGGL(k2b_heads, dim3(512),  dim3(256), 0, stream, feat, off_w, off_b,
                       mask_w, mask_b, offmask);
    hipLaunchKernelGGL(k3_mfma,   dim3(1024), dim3(256), 0, stream, x1, BfIn, in_b, xproj);
    hipLaunchKernelGGL(k45_fused, dim3(512),  dim3(512), 0, stream, xproj, offmask, BfOut,
                       out_b, bn_g, bn_b, bn_mean, bn_var, x1, out);
}